// Round 15
// baseline (458.852 us; speedup 1.0000x reference)
//
#include <hip/hip_runtime.h>

constexpr int NSRC = 50000;
constexpr int NTGT = 10000;
constexpr int NEDGE = 250000;
constexpr int NLBL = 200000;
constexpr int HD = 64;     // hidden dim (per head)
constexpr int NH = 4;      // heads
constexpr int QK = 256;    // HD*NH
constexpr int NTOT = NSRC + NTGT;

typedef __attribute__((ext_vector_type(8))) short bf16x8;
typedef __attribute__((ext_vector_type(4))) float f32x4;

// ---------------- bf16 helpers ----------------
__device__ __forceinline__ unsigned short f2bf(float f) {
  unsigned u = __float_as_uint(f);
  u += 0x7FFFu + ((u >> 16) & 1u);   // round-to-nearest-even
  return (unsigned short)(u >> 16);
}
__device__ __forceinline__ float bf2f(unsigned short b) {
  return __uint_as_float((unsigned)b << 16);
}
struct bf4 { unsigned short x, y, z, w; };
__device__ __forceinline__ float4 bf4_to_f4(bf4 u) {
  return make_float4(bf2f(u.x), bf2f(u.y), bf2f(u.z), bf2f(u.w));
}
__device__ __forceinline__ float lo_f(unsigned u) { return __uint_as_float(u << 16); }
__device__ __forceinline__ float hi_f(unsigned u) { return __uint_as_float(u & 0xFFFF0000u); }

// ---------------- fused setup: weight transpose + feature gather + counts zero ----------------
__global__ __launch_bounds__(256) void setup_kernel(
    const float* __restrict__ Wq, const float* __restrict__ Wk, const float* __restrict__ Wv,
    unsigned short* __restrict__ Wtq, unsigned short* __restrict__ Wtk, unsigned short* __restrict__ Wtv,
    const float* __restrict__ semb, const int* __restrict__ sids,
    const float* __restrict__ temb, const int* __restrict__ tids,
    float* __restrict__ xs, unsigned short* __restrict__ xsb,
    float* __restrict__ xt, unsigned short* __restrict__ xtb,
    int* __restrict__ counts, int nGatherBlk) {
  __shared__ float tile[64][65];
  int b = blockIdx.x;
  int t = threadIdx.x;
  if (b < 48) {
    int mat = b >> 2, ct = b & 3;
    int grp = mat >> 2, p = mat & 3;
    const float* W = (grp == 0) ? Wq : (grp == 1) ? Wk : Wv;
    unsigned short* Wt = (grp == 0) ? Wtq : (grp == 1) ? Wtk : Wtv;
    W += (size_t)p * 16384;
    Wt += (size_t)p * 16384;
    int c = t & 63, r4 = t >> 6;
    for (int rr = 0; rr < 64; rr += 4)
      tile[rr + r4][c] = W[(size_t)(rr + r4) * 256 + ct * 64 + c];
    __syncthreads();
    for (int rr = 0; rr < 64; rr += 4) {
      int nloc = rr + r4;
      Wt[(size_t)(ct * 64 + nloc) * 64 + c] = f2bf(tile[c][nloc]);
    }
  } else if (b < 48 + nGatherBlk) {
    int i = (b - 48) * 256 + t;
    if (i < NSRC * HD) {
      float v = semb[(size_t)sids[i >> 6] * HD + (i & 63)];
      xs[i] = v;
      xsb[i] = f2bf(v);
    } else if (i < NTOT * HD) {
      int j = i - NSRC * HD;
      float v = temb[(size_t)tids[j >> 6] * HD + (j & 63)];
      xt[j] = v;
      xtb[j] = f2bf(v);
    }
  } else {
    int i = (b - 48 - nGatherBlk) * 256 + t;
    if (i < NTOT) counts[i] = 0;
  }
}

// ---------------- CSR build (both edge sets, concatenated counts) ----------------

__global__ __launch_bounds__(256) void hist_all_kernel(const int* __restrict__ e_st, const int* __restrict__ e_ts,
                                                       int* __restrict__ counts) {
  int i = blockIdx.x * 256 + threadIdx.x;
  if (i < NEDGE) atomicAdd(&counts[e_st[NEDGE + i]], 1);
  else if (i < 2 * NEDGE) atomicAdd(&counts[NTGT + e_ts[NEDGE + (i - NEDGE)]], 1);
}

__global__ __launch_bounds__(256) void scan1_kernel(const int* __restrict__ counts, int* __restrict__ incl,
                                                    int* __restrict__ blocksums, int n) {
  __shared__ int wtot[4];
  int t = threadIdx.x;
  int i0 = blockIdx.x * 1024 + t * 4;
  int e0 = (i0 + 0 < n) ? counts[i0 + 0] : 0;
  int e1 = (i0 + 1 < n) ? counts[i0 + 1] : 0;
  int e2 = (i0 + 2 < n) ? counts[i0 + 2] : 0;
  int e3 = (i0 + 3 < n) ? counts[i0 + 3] : 0;
  int s0 = e0, s1 = s0 + e1, s2 = s1 + e2, s3 = s2 + e3;
  int tsum = s3;
  int inc = tsum;
#pragma unroll
  for (int o = 1; o < 64; o <<= 1) {
    int u = __shfl_up(inc, o, 64);
    if ((t & 63) >= o) inc += u;
  }
  int wave = t >> 6;
  if ((t & 63) == 63) wtot[wave] = inc;
  __syncthreads();
  int woff = 0;
#pragma unroll
  for (int w_ = 0; w_ < 4; ++w_) if (w_ < wave) woff += wtot[w_];
  int toff = woff + inc - tsum;
  if (i0 + 0 < n) incl[i0 + 0] = toff + s0;
  if (i0 + 1 < n) incl[i0 + 1] = toff + s1;
  if (i0 + 2 < n) incl[i0 + 2] = toff + s2;
  if (i0 + 3 < n) incl[i0 + 3] = toff + s3;
  if (t == 255) blocksums[blockIdx.x] = woff + inc;
}

__global__ __launch_bounds__(64) void scan2_kernel(const int* __restrict__ blocksums, int* __restrict__ boff, int nb) {
  int t = threadIdx.x;
  int v = (t < nb) ? blocksums[t] : 0;
  int inc = v;
#pragma unroll
  for (int o = 1; o < 64; o <<= 1) {
    int u = __shfl_up(inc, o, 64);
    if (t >= o) inc += u;
  }
  if (t < nb) boff[t] = inc - v;
}

__global__ __launch_bounds__(256) void scan3_kernel(const int* __restrict__ incl, const int* __restrict__ counts,
                                                    const int* __restrict__ boff, int* __restrict__ rp_st,
                                                    int* __restrict__ rp_ts, int* __restrict__ cursor) {
  int i = blockIdx.x * 256 + threadIdx.x;
  if (i < NTOT) {
    int val = incl[i] + boff[i >> 10];
    if (i < NTGT) {
      rp_st[i + 1] = val;
      cursor[i] = val - counts[i];
      if (i == 0) rp_st[0] = 0;
    } else {
      int v2 = val - NEDGE;
      rp_ts[i - NTGT + 1] = v2;
      cursor[i] = v2 - counts[i];
      if (i == NTGT) rp_ts[0] = 0;
    }
  }
}

__global__ __launch_bounds__(256) void scatter_all_kernel(const int* __restrict__ e_st, const int* __restrict__ e_ts,
                                                          int* __restrict__ cursor, int* __restrict__ es_st,
                                                          int* __restrict__ es_ts) {
  int i = blockIdx.x * 256 + threadIdx.x;
  if (i < NEDGE) {
    int d = e_st[NEDGE + i];
    int p = atomicAdd(&cursor[d], 1);
    es_st[p] = e_st[i];
  } else if (i < 2 * NEDGE) {
    int j = i - NEDGE;
    int d = e_ts[NEDGE + j];
    int p = atomicAdd(&cursor[NTGT + d], 1);
    es_ts[p] = e_ts[j];
  }
}

// ---------------- MFMA projection dispatch per layer (kv + q only — R12-proven) ----------------
__global__ __launch_bounds__(256) void proj_all(
    const unsigned short* __restrict__ xsb, const unsigned short* __restrict__ xtb,
    const unsigned short* __restrict__ Wtq, const unsigned short* __restrict__ Wtk,
    const unsigned short* __restrict__ Wtv,
    const float* __restrict__ bq, const float* __restrict__ bk, const float* __restrict__ bv,
    unsigned int* __restrict__ kv_big, unsigned short* __restrict__ q_big,
    unsigned int* __restrict__ kv_small, unsigned short* __restrict__ q_small,
    int p_st, int p_ts) {
  constexpr int B1 = NSRC / 16;   // 3125
  constexpr int B2 = NTGT / 16;   // 625
  int b = blockIdx.x;
  int w = threadIdx.x >> 6, l = threadIdx.x & 63;
  int m = l & 15, qd = l >> 4;
  const unsigned short* xb; const unsigned short* WtA; const unsigned short* WtB = nullptr;
  const float* biasA; const float* biasB = nullptr;
  unsigned int* okv = nullptr; unsigned short* oq = nullptr;
  int R0, mode;
  if (b < B1) {                       // kv_s (params p_st)
    xb = xsb; R0 = b * 16; mode = 0;
    WtA = Wtk + (size_t)p_st * 16384; biasA = bk + p_st * 256;
    WtB = Wtv + (size_t)p_st * 16384; biasB = bv + p_st * 256;
    okv = kv_big;
  } else if (b < B1 + B2) {           // kv_t (params p_ts)
    xb = xtb; R0 = (b - B1) * 16; mode = 0;
    WtA = Wtk + (size_t)p_ts * 16384; biasA = bk + p_ts * 256;
    WtB = Wtv + (size_t)p_ts * 16384; biasB = bv + p_ts * 256;
    okv = kv_small;
  } else if (b < 2 * B1 + B2) {       // q_s (params p_ts)
    xb = xsb; R0 = (b - B1 - B2) * 16; mode = 1;
    WtA = Wtq + (size_t)p_ts * 16384; biasA = bq + p_ts * 256;
    oq = q_big;
  } else {                            // q_t (params p_st)
    xb = xtb; R0 = (b - 2 * B1 - B2) * 16; mode = 1;
    WtA = Wtq + (size_t)p_st * 16384; biasA = bq + p_st * 256;
    oq = q_small;
  }
  const unsigned short* xrow = xb + (size_t)(R0 + m) * 64 + qd * 8;
  bf16x8 a_lo = *(const bf16x8*)xrow;
  bf16x8 a_hi = *(const bf16x8*)(xrow + 32);
  if (mode == 0) {
#pragma unroll
    for (int i = 0; i < 4; ++i) {
      int col = (w * 4 + i) * 16 + m;
      const unsigned short* wk = WtA + (size_t)col * 64 + qd * 8;
      const unsigned short* wv = WtB + (size_t)col * 64 + qd * 8;
      bf16x8 bk_lo = *(const bf16x8*)wk, bk_hi = *(const bf16x8*)(wk + 32);
      bf16x8 bv_lo = *(const bf16x8*)wv, bv_hi = *(const bf16x8*)(wv + 32);
      f32x4 ak = {0.f, 0.f, 0.f, 0.f}, av = {0.f, 0.f, 0.f, 0.f};
      ak = __builtin_amdgcn_mfma_f32_16x16x32_bf16(a_lo, bk_lo, ak, 0, 0, 0);
      ak = __builtin_amdgcn_mfma_f32_16x16x32_bf16(a_hi, bk_hi, ak, 0, 0, 0);
      av = __builtin_amdgcn_mfma_f32_16x16x32_bf16(a_lo, bv_lo, av, 0, 0, 0);
      av = __builtin_amdgcn_mfma_f32_16x16x32_bf16(a_hi, bv_hi, av, 0, 0, 0);
      float bkc = biasA[col], bvc = biasB[col];
      unsigned int* obase = okv + (size_t)(R0 + qd * 4) * 256 + col;
#pragma unroll
      for (int r = 0; r < 4; ++r) {
        unsigned word = (unsigned)f2bf(ak[r] + bkc) | ((unsigned)f2bf(av[r] + bvc) << 16);
        obase[(size_t)r * 256] = word;
      }
    }
  } else {
#pragma unroll
    for (int i = 0; i < 4; ++i) {
      int col = (w * 4 + i) * 16 + m;
      const unsigned short* wq = WtA + (size_t)col * 64 + qd * 8;
      bf16x8 b_lo = *(const bf16x8*)wq, b_hi = *(const bf16x8*)(wq + 32);
      f32x4 acc = {0.f, 0.f, 0.f, 0.f};
      acc = __builtin_amdgcn_mfma_f32_16x16x32_bf16(a_lo, b_lo, acc, 0, 0, 0);
      acc = __builtin_amdgcn_mfma_f32_16x16x32_bf16(a_hi, b_hi, acc, 0, 0, 0);
      float bc = biasA[col];
      unsigned short* obase = oq + (size_t)(R0 + qd * 4) * 256 + col;
#pragma unroll
      for (int r = 0; r < 4; ++r)
        obase[(size_t)r * 256] = f2bf(acc[r] + bc);
    }
  }
}

// ---------------- fused fp32 skip GEMM for both directions (LDS-tiled, R12-proven) ----------------
__global__ __launch_bounds__(256) void skip_all(const float* __restrict__ xs, const float* __restrict__ xt,
    const float* __restrict__ Wsk, const float* __restrict__ bsk,
    float* __restrict__ xs_nxt, float* __restrict__ xt_nxt, int p_st, int p_ts, int rtS) {
  __shared__ float Xt[64][68];
  __shared__ float Wl[64][68];
  __shared__ float bias[64];
  int t = threadIdx.x;
  const float* x; const float* W; const float* bb; float* o; int N, rbase;
  if ((int)blockIdx.x < rtS) {
    x = xs; N = NSRC; rbase = blockIdx.x * 64;
    W = Wsk + (size_t)p_ts * 4096; bb = bsk + p_ts * 64; o = xs_nxt;
  } else {
    x = xt; N = NTGT; rbase = (blockIdx.x - rtS) * 64;
    W = Wsk + (size_t)p_st * 4096; bb = bsk + p_st * 64; o = xt_nxt;
  }
#pragma unroll
  for (int i = 0; i < 4; ++i) {
    int slot = i * 256 + t;
    int row = slot >> 4;
    int k4 = slot & 15;
    float4 xv = make_float4(0.f, 0.f, 0.f, 0.f);
    if (rbase + row < N) xv = *(const float4*)&x[(size_t)(rbase + row) * 64 + k4 * 4];
    Xt[k4 * 4 + 0][row] = xv.x;
    Xt[k4 * 4 + 1][row] = xv.y;
    Xt[k4 * 4 + 2][row] = xv.z;
    Xt[k4 * 4 + 3][row] = xv.w;
  }
#pragma unroll
  for (int i = 0; i < 4; ++i) {
    int slot = i * 256 + t;
    int kk = slot >> 4;
    int c4 = slot & 15;
    float4 wv = *(const float4*)&W[(size_t)kk * 64 + c4 * 4];
    *(float4*)&Wl[kk][c4 * 4] = wv;
  }
  if (t < 64) bias[t] = bb[t];
  __syncthreads();

  int c0 = (t & 15) * 4;
  int r0 = (t >> 4) * 4;
  float acc[4][4];
#pragma unroll
  for (int i = 0; i < 4; ++i)
#pragma unroll
    for (int j = 0; j < 4; ++j) acc[i][j] = 0.f;
#pragma unroll 8
  for (int kk = 0; kk < 64; ++kk) {
    float4 xv = *(const float4*)&Xt[kk][r0];
    float4 wv = *(const float4*)&Wl[kk][c0];
    float xr[4] = {xv.x, xv.y, xv.z, xv.w};
    float wc[4] = {wv.x, wv.y, wv.z, wv.w};
#pragma unroll
    for (int i = 0; i < 4; ++i)
#pragma unroll
      for (int j = 0; j < 4; ++j) acc[i][j] = fmaf(xr[i], wc[j], acc[i][j]);
  }
#pragma unroll
  for (int i = 0; i < 4; ++i) {
    int row = rbase + r0 + i;
    if (row < N) {
      float4 ov;
      ov.x = acc[i][0] + bias[c0 + 0];
      ov.y = acc[i][1] + bias[c0 + 1];
      ov.z = acc[i][2] + bias[c0 + 2];
      ov.w = acc[i][3] + bias[c0 + 3];
      *(float4*)&o[(size_t)row * 64 + c0] = ov;
    }
  }
}

// ---------------- fused aggregation, both directions, software-pipelined edge loop ----------------
// one WAVE per node; batch of 4 edges; batch i+1's eisrc + kv gathers issued before
// computing batch i (double the outstanding loads in the latency-bound regime).
__global__ __launch_bounds__(256) void agg_all(
    const unsigned short* __restrict__ q_small, const unsigned short* __restrict__ kv_big,
    const int* __restrict__ rp_st, const int* __restrict__ es_st,
    float* __restrict__ xt_nxt, unsigned short* __restrict__ xtb_nxt,
    const unsigned short* __restrict__ q_big, const unsigned short* __restrict__ kv_small,
    const int* __restrict__ rp_ts, const int* __restrict__ es_ts,
    float* __restrict__ xs_nxt, unsigned short* __restrict__ xsb_nxt,
    int relu, int stBlocks) {
  const unsigned short* q; const unsigned short* kvi; const int* rowptr; const int* eisrc;
  float* xout; unsigned short* xoutb; int node;
  int wv = threadIdx.x >> 6, l = threadIdx.x & 63;
  if ((int)blockIdx.x < stBlocks) {
    node = blockIdx.x * 4 + wv;
    if (node >= NTGT) return;
    q = q_small; kvi = kv_big; rowptr = rp_st; eisrc = es_st; xout = xt_nxt; xoutb = xtb_nxt;
  } else {
    node = (blockIdx.x - stBlocks) * 4 + wv;
    if (node >= NSRC) return;
    q = q_big; kvi = kv_small; rowptr = rp_ts; eisrc = es_ts; xout = xs_nxt; xoutb = xsb_nxt;
  }
  int j = l & 15;
  float4 qf = bf4_to_f4(*(const bf4*)&q[(size_t)node * QK + l * 4]);
  qf.x *= 0.125f; qf.y *= 0.125f; qf.z *= 0.125f; qf.w *= 0.125f;
  int beg = rowptr[node], end = rowptr[node + 1];

  float lsum = 0.f;
  float4 acc = make_float4(0.f, 0.f, 0.f, 0.f);
  int n4 = (end - beg) >> 2;
  int p = beg;
  uint4 A0, A1, A2, A3;
  if (n4 > 0) {
    int s0 = eisrc[p], s1 = eisrc[p + 1], s2 = eisrc[p + 2], s3 = eisrc[p + 3];
    A0 = *(const uint4*)&kvi[(size_t)s0 * 512 + l * 8];
    A1 = *(const uint4*)&kvi[(size_t)s1 * 512 + l * 8];
    A2 = *(const uint4*)&kvi[(size_t)s2 * 512 + l * 8];
    A3 = *(const uint4*)&kvi[(size_t)s3 * 512 + l * 8];
  }
  for (int it = 0; it < n4; ++it) {
    uint4 B0, B1, B2, B3;
    bool more = (it + 1 < n4);
    if (more) {
      int s0 = eisrc[p + 4], s1 = eisrc[p + 5], s2 = eisrc[p + 6], s3 = eisrc[p + 7];
      B0 = *(const uint4*)&kvi[(size_t)s0 * 512 + l * 8];
      B1 = *(const uint4*)&kvi[(size_t)s1 * 512 + l * 8];
      B2 = *(const uint4*)&kvi[(size_t)s2 * 512 + l * 8];
      B3 = *(const uint4*)&kvi[(size_t)s3 * 512 + l * 8];
    }
    float t0 = qf.x * lo_f(A0.x) + qf.y * lo_f(A0.y) + qf.z * lo_f(A0.z) + qf.w * lo_f(A0.w);
    float t1 = qf.x * lo_f(A1.x) + qf.y * lo_f(A1.y) + qf.z * lo_f(A1.z) + qf.w * lo_f(A1.w);
    float t2 = qf.x * lo_f(A2.x) + qf.y * lo_f(A2.y) + qf.z * lo_f(A2.z) + qf.w * lo_f(A2.w);
    float t3 = qf.x * lo_f(A3.x) + qf.y * lo_f(A3.y) + qf.z * lo_f(A3.z) + qf.w * lo_f(A3.w);
#pragma unroll
    for (int o = 1; o < 16; o <<= 1) {
      t0 += __shfl_xor(t0, o, 16); t1 += __shfl_xor(t1, o, 16);
      t2 += __shfl_xor(t2, o, 16); t3 += __shfl_xor(t3, o, 16);
    }
    float w0 = __expf(t0), w1 = __expf(t1), w2 = __expf(t2), w3 = __expf(t3);
    lsum += (w0 + w1) + (w2 + w3);
    acc.x = fmaf(w0, hi_f(A0.x), fmaf(w1, hi_f(A1.x), fmaf(w2, hi_f(A2.x), fmaf(w3, hi_f(A3.x), acc.x))));
    acc.y = fmaf(w0, hi_f(A0.y), fmaf(w1, hi_f(A1.y), fmaf(w2, hi_f(A2.y), fmaf(w3, hi_f(A3.y), acc.y))));
    acc.z = fmaf(w0, hi_f(A0.z), fmaf(w1, hi_f(A1.z), fmaf(w2, hi_f(A2.z), fmaf(w3, hi_f(A3.z), acc.z))));
    acc.w = fmaf(w0, hi_f(A0.w), fmaf(w1, hi_f(A1.w), fmaf(w2, hi_f(A2.w), fmaf(w3, hi_f(A3.w), acc.w))));
    if (more) { A0 = B0; A1 = B1; A2 = B2; A3 = B3; }
    p += 4;
  }
  for (; p < end; ++p) {
    int s0 = eisrc[p];
    uint4 a0 = *(const uint4*)&kvi[(size_t)s0 * 512 + l * 8];
    float s = qf.x * lo_f(a0.x) + qf.y * lo_f(a0.y) + qf.z * lo_f(a0.z) + qf.w * lo_f(a0.w);
#pragma unroll
    for (int o = 1; o < 16; o <<= 1) s += __shfl_xor(s, o, 16);
    float w = __expf(s);
    lsum += w;
    acc.x = fmaf(w, hi_f(a0.x), acc.x);
    acc.y = fmaf(w, hi_f(a0.y), acc.y);
    acc.z = fmaf(w, hi_f(a0.z), acc.z);
    acc.w = fmaf(w, hi_f(a0.w), acc.w);
  }

  float inv = (lsum > 0.f) ? 1.f / lsum : 0.f;
  float4 r;
  r.x = acc.x * inv; r.y = acc.y * inv; r.z = acc.z * inv; r.w = acc.w * inv;
  r.x += __shfl_xor(r.x, 16, 64); r.x += __shfl_xor(r.x, 32, 64);
  r.y += __shfl_xor(r.y, 16, 64); r.y += __shfl_xor(r.y, 32, 64);
  r.z += __shfl_xor(r.z, 16, 64); r.z += __shfl_xor(r.z, 32, 64);
  r.w += __shfl_xor(r.w, 16, 64); r.w += __shfl_xor(r.w, 32, 64);
  if (l < 16) {
    float4 sk = *(const float4*)&xout[(size_t)node * HD + j * 4];
    float4 o;
    o.x = sk.x + 0.25f * r.x;
    o.y = sk.y + 0.25f * r.y;
    o.z = sk.z + 0.25f * r.z;
    o.w = sk.w + 0.25f * r.w;
    if (relu) {
      o.x = fmaxf(o.x, 0.f); o.y = fmaxf(o.y, 0.f);
      o.z = fmaxf(o.z, 0.f); o.w = fmaxf(o.w, 0.f);
    }
    *(float4*)&xout[(size_t)node * HD + j * 4] = o;
    bf4 ob;
    ob.x = f2bf(o.x); ob.y = f2bf(o.y); ob.z = f2bf(o.z); ob.w = f2bf(o.w);
    *(bf4*)&xoutb[(size_t)node * HD + j * 4] = ob;
  }
}

// ---------------- classifier: 16 lanes per pair, float4 loads ----------------
__global__ __launch_bounds__(256) void classifier_kernel(const float* __restrict__ xs, const float* __restrict__ xt,
    const int* __restrict__ ls, const int* __restrict__ lt, float* __restrict__ out, int n) {
  int g = blockIdx.x * 256 + threadIdx.x;
  int pair = g >> 4, j = g & 15;
  if (pair >= n) return;
  int a = ls[pair], b = lt[pair];
  float4 xa = *(const float4*)&xs[(size_t)a * HD + j * 4];
  float4 xb = *(const float4*)&xt[(size_t)b * HD + j * 4];
  float s = xa.x * xb.x + xa.y * xb.y + xa.z * xb.z + xa.w * xb.w;
#pragma unroll
  for (int o = 1; o < 16; o <<= 1) s += __shfl_xor(s, o, 16);
  if (j == 0) out[pair] = s;
}

// ---------------- launch ----------------
extern "C" void kernel_launch(void* const* d_in, const int* in_sizes, int n_in,
                              void* d_out, int out_size, void* d_ws, size_t ws_size,
                              hipStream_t stream) {
  const float* src_emb = (const float*)d_in[0];
  const float* tgt_emb = (const float*)d_in[1];
  const float* Wq = (const float*)d_in[2];
  const float* bq = (const float*)d_in[3];
  const float* Wk = (const float*)d_in[4];
  const float* bk = (const float*)d_in[5];
  const float* Wv = (const float*)d_in[6];
  const float* bv = (const float*)d_in[7];
  const float* Wsk = (const float*)d_in[8];
  const float* bsk = (const float*)d_in[9];
  const int* nid_s = (const int*)d_in[10];
  const int* nid_t = (const int*)d_in[11];
  const int* e_st = (const int*)d_in[12];
  const int* e_ts = (const int*)d_in[13];
  const int* e_lbl = (const int*)d_in[14];
  float* out = (float*)d_out;

  char* ws = (char*)d_ws;
  size_t off = 0;
  auto alloc = [&](size_t bytes) -> void* {
    void* p = ws + off;
    off += (bytes + 255) & ~(size_t)255;
    return p;
  };
  unsigned int*   kv_big   = (unsigned int*)alloc((size_t)NSRC * 256 * 4);   // st k/v packed words
  unsigned short* q_big    = (unsigned short*)alloc((size_t)NSRC * QK * 2);  // ts q
  unsigned int*   kv_small = (unsigned int*)alloc((size_t)NTGT * 256 * 4);   // ts k/v packed words
  unsigned short* q_small  = (unsigned short*)alloc((size_t)NTGT * QK * 2);  // st q
  float* xsA = (float*)alloc((size_t)NSRC * HD * 4);
  float* xsB = (float*)alloc((size_t)NSRC * HD * 4);
  float* xtA = (float*)alloc((size_t)NTGT * HD * 4);
  float* xtB = (float*)alloc((size_t)NTGT * HD * 4);
  unsigned short* xsAb = (unsigned short*)alloc((size_t)NSRC * HD * 2);
  unsigned short* xsBb = (unsigned short*)alloc((size_t)NSRC * HD * 2);
  unsigned short* xtAb = (unsigned short*)alloc((size_t)NTGT * HD * 2);
  unsigned short* xtBb = (unsigned short*)alloc((size_t)NTGT * HD * 2);
  unsigned short* Wtq = (unsigned short*)alloc((size_t)4 * 16384 * 2);
  unsigned short* Wtk = (unsigned short*)alloc((size_t)4 * 16384 * 2);
  unsigned short* Wtv = (unsigned short*)alloc((size_t)4 * 16384 * 2);
  int* rp_st = (int*)alloc((size_t)(NTGT + 1) * 4);
  int* es_st = (int*)alloc((size_t)NEDGE * 4);
  int* rp_ts = (int*)alloc((size_t)(NSRC + 1) * 4);
  int* es_ts = (int*)alloc((size_t)NEDGE * 4);
  int* cursor = (int*)alloc((size_t)NTOT * 4);
  int* counts = (int*)alloc((size_t)NTOT * 4);
  int* incl_buf = (int*)alloc((size_t)NTOT * 4);
  int* blocksums = (int*)alloc(64 * 4);
  int* boff = (int*)alloc(64 * 4);
  (void)ws_size; (void)in_sizes; (void)n_in; (void)out_size;

  auto cdiv = [](int a, int b) { return (a + b - 1) / b; };
  const int GATHER_BLK = cdiv(NTOT * HD, 256);          // 15000
  const int SETUP_BLK = 48 + GATHER_BLK + cdiv(NTOT, 256);
  const int RT_S = cdiv(NSRC, 64);                      // 782
  const int RT_T = cdiv(NTGT, 64);                      // 157
  const int NBLK_PROJ = 2 * (NSRC / 16) + 2 * (NTGT / 16);  // kv+q = 7500
  const int ST_BLK = cdiv(NTGT, 4);                     // 2500
  const int NBLK_AGG = ST_BLK + cdiv(NSRC, 4);          // 15000

  // fused setup: weight transpose + feature gather + counts zero
  setup_kernel<<<SETUP_BLK, 256, 0, stream>>>(Wq, Wk, Wv, Wtq, Wtk, Wtv,
                                              src_emb, nid_s, tgt_emb, nid_t,
                                              xsA, xsAb, xtA, xtAb, counts, GATHER_BLK);

  // CSR build for both edge sets
  hist_all_kernel<<<cdiv(2 * NEDGE, 256), 256, 0, stream>>>(e_st, e_ts, counts);
  scan1_kernel<<<cdiv(NTOT, 1024), 256, 0, stream>>>(counts, incl_buf, blocksums, NTOT);
  scan2_kernel<<<1, 64, 0, stream>>>(blocksums, boff, cdiv(NTOT, 1024));
  scan3_kernel<<<cdiv(NTOT, 256), 256, 0, stream>>>(incl_buf, counts, boff, rp_st, rp_ts, cursor);
  scatter_all_kernel<<<cdiv(2 * NEDGE, 256), 256, 0, stream>>>(e_st, e_ts, cursor, es_st, es_ts);

  const float* xs_cur = xsA; float* xs_nxt = xsB;
  const float* xt_cur = xtA; float* xt_nxt = xtB;
  const unsigned short* xsb_cur = xsAb; unsigned short* xsb_nxt = xsBb;
  const unsigned short* xtb_cur = xtAb; unsigned short* xtb_nxt = xtBb;
  for (int l = 0; l < 2; ++l) {
    int relu = (l == 0) ? 1 : 0;
    int p_st = l * 2 + 0, p_ts = l * 2 + 1;
    proj_all<<<NBLK_PROJ, 256, 0, stream>>>(xsb_cur, xtb_cur, Wtq, Wtk, Wtv, bq, bk, bv,
                                            kv_big, q_big, kv_small, q_small, p_st, p_ts);
    skip_all<<<RT_S + RT_T, 256, 0, stream>>>(xs_cur, xt_cur, Wsk, bsk, xs_nxt, xt_nxt, p_st, p_ts, RT_S);
    agg_all<<<NBLK_AGG, 256, 0, stream>>>(q_small, (const unsigned short*)kv_big, rp_st, es_st, xt_nxt, xtb_nxt,
                                          q_big, (const unsigned short*)kv_small, rp_ts, es_ts, xs_nxt, xsb_nxt,
                                          relu, ST_BLK);
    { const float* t = xs_nxt; xs_nxt = (float*)xs_cur; xs_cur = t; }
    { const float* t = xt_nxt; xt_nxt = (float*)xt_cur; xt_cur = t; }
    { const unsigned short* t = xsb_nxt; xsb_nxt = (unsigned short*)xsb_cur; xsb_cur = t; }
    { const unsigned short* t = xtb_nxt; xtb_nxt = (unsigned short*)xtb_cur; xtb_cur = t; }
  }

  classifier_kernel<<<cdiv(NLBL * 16, 256), 256, 0, stream>>>(xs_cur, xt_cur, e_lbl, e_lbl + NLBL, out, NLBL);
}

// Round 16
// 442.659 us; speedup vs baseline: 1.0366x; 1.0366x over previous
//
#include <hip/hip_runtime.h>

constexpr int NSRC = 50000;
constexpr int NTGT = 10000;
constexpr int NEDGE = 250000;
constexpr int NLBL = 200000;
constexpr int HD = 64;     // hidden dim (per head)
constexpr int NH = 4;      // heads
constexpr int QK = 256;    // HD*NH
constexpr int NTOT = NSRC + NTGT;

typedef __attribute__((ext_vector_type(8))) short bf16x8;
typedef __attribute__((ext_vector_type(4))) float f32x4;

// ---------------- bf16 helpers ----------------
__device__ __forceinline__ unsigned short f2bf(float f) {
  unsigned u = __float_as_uint(f);
  u += 0x7FFFu + ((u >> 16) & 1u);   // round-to-nearest-even
  return (unsigned short)(u >> 16);
}
__device__ __forceinline__ float bf2f(unsigned short b) {
  return __uint_as_float((unsigned)b << 16);
}
struct bf4 { unsigned short x, y, z, w; };
__device__ __forceinline__ float4 bf4_to_f4(bf4 u) {
  return make_float4(bf2f(u.x), bf2f(u.y), bf2f(u.z), bf2f(u.w));
}
__device__ __forceinline__ float lo_f(unsigned u) { return __uint_as_float(u << 16); }
__device__ __forceinline__ float hi_f(unsigned u) { return __uint_as_float(u & 0xFFFF0000u); }

// ---------------- fused setup: weight transpose + feature gather + counts zero ----------------
__global__ __launch_bounds__(256) void setup_kernel(
    const float* __restrict__ Wq, const float* __restrict__ Wk, const float* __restrict__ Wv,
    unsigned short* __restrict__ Wtq, unsigned short* __restrict__ Wtk, unsigned short* __restrict__ Wtv,
    const float* __restrict__ semb, const int* __restrict__ sids,
    const float* __restrict__ temb, const int* __restrict__ tids,
    float* __restrict__ xs, unsigned short* __restrict__ xsb,
    float* __restrict__ xt, unsigned short* __restrict__ xtb,
    int* __restrict__ counts, int nGatherBlk) {
  __shared__ float tile[64][65];
  int b = blockIdx.x;
  int t = threadIdx.x;
  if (b < 48) {
    int mat = b >> 2, ct = b & 3;
    int grp = mat >> 2, p = mat & 3;
    const float* W = (grp == 0) ? Wq : (grp == 1) ? Wk : Wv;
    unsigned short* Wt = (grp == 0) ? Wtq : (grp == 1) ? Wtk : Wtv;
    W += (size_t)p * 16384;
    Wt += (size_t)p * 16384;
    int c = t & 63, r4 = t >> 6;
    for (int rr = 0; rr < 64; rr += 4)
      tile[rr + r4][c] = W[(size_t)(rr + r4) * 256 + ct * 64 + c];
    __syncthreads();
    for (int rr = 0; rr < 64; rr += 4) {
      int nloc = rr + r4;
      Wt[(size_t)(ct * 64 + nloc) * 64 + c] = f2bf(tile[c][nloc]);
    }
  } else if (b < 48 + nGatherBlk) {
    int i = (b - 48) * 256 + t;
    if (i < NSRC * HD) {
      float v = semb[(size_t)sids[i >> 6] * HD + (i & 63)];
      xs[i] = v;
      xsb[i] = f2bf(v);
    } else if (i < NTOT * HD) {
      int j = i - NSRC * HD;
      float v = temb[(size_t)tids[j >> 6] * HD + (j & 63)];
      xt[j] = v;
      xtb[j] = f2bf(v);
    }
  } else {
    int i = (b - 48 - nGatherBlk) * 256 + t;
    if (i < NTOT) counts[i] = 0;
  }
}

// ---------------- CSR build (both edge sets, concatenated counts) ----------------

__global__ __launch_bounds__(256) void hist_all_kernel(const int* __restrict__ e_st, const int* __restrict__ e_ts,
                                                       int* __restrict__ counts) {
  int i = blockIdx.x * 256 + threadIdx.x;
  if (i < NEDGE) atomicAdd(&counts[e_st[NEDGE + i]], 1);
  else if (i < 2 * NEDGE) atomicAdd(&counts[NTGT + e_ts[NEDGE + (i - NEDGE)]], 1);
}

__global__ __launch_bounds__(256) void scan1_kernel(const int* __restrict__ counts, int* __restrict__ incl,
                                                    int* __restrict__ blocksums, int n) {
  __shared__ int wtot[4];
  int t = threadIdx.x;
  int i0 = blockIdx.x * 1024 + t * 4;
  int e0 = (i0 + 0 < n) ? counts[i0 + 0] : 0;
  int e1 = (i0 + 1 < n) ? counts[i0 + 1] : 0;
  int e2 = (i0 + 2 < n) ? counts[i0 + 2] : 0;
  int e3 = (i0 + 3 < n) ? counts[i0 + 3] : 0;
  int s0 = e0, s1 = s0 + e1, s2 = s1 + e2, s3 = s2 + e3;
  int tsum = s3;
  int inc = tsum;
#pragma unroll
  for (int o = 1; o < 64; o <<= 1) {
    int u = __shfl_up(inc, o, 64);
    if ((t & 63) >= o) inc += u;
  }
  int wave = t >> 6;
  if ((t & 63) == 63) wtot[wave] = inc;
  __syncthreads();
  int woff = 0;
#pragma unroll
  for (int w_ = 0; w_ < 4; ++w_) if (w_ < wave) woff += wtot[w_];
  int toff = woff + inc - tsum;
  if (i0 + 0 < n) incl[i0 + 0] = toff + s0;
  if (i0 + 1 < n) incl[i0 + 1] = toff + s1;
  if (i0 + 2 < n) incl[i0 + 2] = toff + s2;
  if (i0 + 3 < n) incl[i0 + 3] = toff + s3;
  if (t == 255) blocksums[blockIdx.x] = woff + inc;
}

__global__ __launch_bounds__(64) void scan2_kernel(const int* __restrict__ blocksums, int* __restrict__ boff, int nb) {
  int t = threadIdx.x;
  int v = (t < nb) ? blocksums[t] : 0;
  int inc = v;
#pragma unroll
  for (int o = 1; o < 64; o <<= 1) {
    int u = __shfl_up(inc, o, 64);
    if (t >= o) inc += u;
  }
  if (t < nb) boff[t] = inc - v;
}

__global__ __launch_bounds__(256) void scan3_kernel(const int* __restrict__ incl, const int* __restrict__ counts,
                                                    const int* __restrict__ boff, int* __restrict__ rp_st,
                                                    int* __restrict__ rp_ts, int* __restrict__ cursor) {
  int i = blockIdx.x * 256 + threadIdx.x;
  if (i < NTOT) {
    int val = incl[i] + boff[i >> 10];
    if (i < NTGT) {
      rp_st[i + 1] = val;
      cursor[i] = val - counts[i];
      if (i == 0) rp_st[0] = 0;
    } else {
      int v2 = val - NEDGE;
      rp_ts[i - NTGT + 1] = v2;
      cursor[i] = v2 - counts[i];
      if (i == NTGT) rp_ts[0] = 0;
    }
  }
}

__global__ __launch_bounds__(256) void scatter_all_kernel(const int* __restrict__ e_st, const int* __restrict__ e_ts,
                                                          int* __restrict__ cursor, int* __restrict__ es_st,
                                                          int* __restrict__ es_ts) {
  int i = blockIdx.x * 256 + threadIdx.x;
  if (i < NEDGE) {
    int d = e_st[NEDGE + i];
    int p = atomicAdd(&cursor[d], 1);
    es_st[p] = e_st[i];
  } else if (i < 2 * NEDGE) {
    int j = i - NEDGE;
    int d = e_ts[NEDGE + j];
    int p = atomicAdd(&cursor[NTGT + d], 1);
    es_ts[p] = e_ts[j];
  }
}

// ---------------- MFMA projection dispatch per layer (kv + q only — R12-proven) ----------------
__global__ __launch_bounds__(256) void proj_all(
    const unsigned short* __restrict__ xsb, const unsigned short* __restrict__ xtb,
    const unsigned short* __restrict__ Wtq, const unsigned short* __restrict__ Wtk,
    const unsigned short* __restrict__ Wtv,
    const float* __restrict__ bq, const float* __restrict__ bk, const float* __restrict__ bv,
    unsigned int* __restrict__ kv_big, unsigned short* __restrict__ q_big,
    unsigned int* __restrict__ kv_small, unsigned short* __restrict__ q_small,
    int p_st, int p_ts) {
  constexpr int B1 = NSRC / 16;   // 3125
  constexpr int B2 = NTGT / 16;   // 625
  int b = blockIdx.x;
  int w = threadIdx.x >> 6, l = threadIdx.x & 63;
  int m = l & 15, qd = l >> 4;
  const unsigned short* xb; const unsigned short* WtA; const unsigned short* WtB = nullptr;
  const float* biasA; const float* biasB = nullptr;
  unsigned int* okv = nullptr; unsigned short* oq = nullptr;
  int R0, mode;
  if (b < B1) {                       // kv_s (params p_st)
    xb = xsb; R0 = b * 16; mode = 0;
    WtA = Wtk + (size_t)p_st * 16384; biasA = bk + p_st * 256;
    WtB = Wtv + (size_t)p_st * 16384; biasB = bv + p_st * 256;
    okv = kv_big;
  } else if (b < B1 + B2) {           // kv_t (params p_ts)
    xb = xtb; R0 = (b - B1) * 16; mode = 0;
    WtA = Wtk + (size_t)p_ts * 16384; biasA = bk + p_ts * 256;
    WtB = Wtv + (size_t)p_ts * 16384; biasB = bv + p_ts * 256;
    okv = kv_small;
  } else if (b < 2 * B1 + B2) {       // q_s (params p_ts)
    xb = xsb; R0 = (b - B1 - B2) * 16; mode = 1;
    WtA = Wtq + (size_t)p_ts * 16384; biasA = bq + p_ts * 256;
    oq = q_big;
  } else {                            // q_t (params p_st)
    xb = xtb; R0 = (b - 2 * B1 - B2) * 16; mode = 1;
    WtA = Wtq + (size_t)p_st * 16384; biasA = bq + p_st * 256;
    oq = q_small;
  }
  const unsigned short* xrow = xb + (size_t)(R0 + m) * 64 + qd * 8;
  bf16x8 a_lo = *(const bf16x8*)xrow;
  bf16x8 a_hi = *(const bf16x8*)(xrow + 32);
  if (mode == 0) {
#pragma unroll
    for (int i = 0; i < 4; ++i) {
      int col = (w * 4 + i) * 16 + m;
      const unsigned short* wk = WtA + (size_t)col * 64 + qd * 8;
      const unsigned short* wv = WtB + (size_t)col * 64 + qd * 8;
      bf16x8 bk_lo = *(const bf16x8*)wk, bk_hi = *(const bf16x8*)(wk + 32);
      bf16x8 bv_lo = *(const bf16x8*)wv, bv_hi = *(const bf16x8*)(wv + 32);
      f32x4 ak = {0.f, 0.f, 0.f, 0.f}, av = {0.f, 0.f, 0.f, 0.f};
      ak = __builtin_amdgcn_mfma_f32_16x16x32_bf16(a_lo, bk_lo, ak, 0, 0, 0);
      ak = __builtin_amdgcn_mfma_f32_16x16x32_bf16(a_hi, bk_hi, ak, 0, 0, 0);
      av = __builtin_amdgcn_mfma_f32_16x16x32_bf16(a_lo, bv_lo, av, 0, 0, 0);
      av = __builtin_amdgcn_mfma_f32_16x16x32_bf16(a_hi, bv_hi, av, 0, 0, 0);
      float bkc = biasA[col], bvc = biasB[col];
      unsigned int* obase = okv + (size_t)(R0 + qd * 4) * 256 + col;
#pragma unroll
      for (int r = 0; r < 4; ++r) {
        unsigned word = (unsigned)f2bf(ak[r] + bkc) | ((unsigned)f2bf(av[r] + bvc) << 16);
        obase[(size_t)r * 256] = word;
      }
    }
  } else {
#pragma unroll
    for (int i = 0; i < 4; ++i) {
      int col = (w * 4 + i) * 16 + m;
      const unsigned short* wq = WtA + (size_t)col * 64 + qd * 8;
      bf16x8 b_lo = *(const bf16x8*)wq, b_hi = *(const bf16x8*)(wq + 32);
      f32x4 acc = {0.f, 0.f, 0.f, 0.f};
      acc = __builtin_amdgcn_mfma_f32_16x16x32_bf16(a_lo, b_lo, acc, 0, 0, 0);
      acc = __builtin_amdgcn_mfma_f32_16x16x32_bf16(a_hi, b_hi, acc, 0, 0, 0);
      float bc = biasA[col];
      unsigned short* obase = oq + (size_t)(R0 + qd * 4) * 256 + col;
#pragma unroll
      for (int r = 0; r < 4; ++r)
        obase[(size_t)r * 256] = f2bf(acc[r] + bc);
    }
  }
}

// ---------------- fused fp32 skip GEMM for both directions (LDS-tiled, R12-proven) ----------------
__global__ __launch_bounds__(256) void skip_all(const float* __restrict__ xs, const float* __restrict__ xt,
    const float* __restrict__ Wsk, const float* __restrict__ bsk,
    float* __restrict__ xs_nxt, float* __restrict__ xt_nxt, int p_st, int p_ts, int rtS) {
  __shared__ float Xt[64][68];
  __shared__ float Wl[64][68];
  __shared__ float bias[64];
  int t = threadIdx.x;
  const float* x; const float* W; const float* bb; float* o; int N, rbase;
  if ((int)blockIdx.x < rtS) {
    x = xs; N = NSRC; rbase = blockIdx.x * 64;
    W = Wsk + (size_t)p_ts * 4096; bb = bsk + p_ts * 64; o = xs_nxt;
  } else {
    x = xt; N = NTGT; rbase = (blockIdx.x - rtS) * 64;
    W = Wsk + (size_t)p_st * 4096; bb = bsk + p_st * 64; o = xt_nxt;
  }
#pragma unroll
  for (int i = 0; i < 4; ++i) {
    int slot = i * 256 + t;
    int row = slot >> 4;
    int k4 = slot & 15;
    float4 xv = make_float4(0.f, 0.f, 0.f, 0.f);
    if (rbase + row < N) xv = *(const float4*)&x[(size_t)(rbase + row) * 64 + k4 * 4];
    Xt[k4 * 4 + 0][row] = xv.x;
    Xt[k4 * 4 + 1][row] = xv.y;
    Xt[k4 * 4 + 2][row] = xv.z;
    Xt[k4 * 4 + 3][row] = xv.w;
  }
#pragma unroll
  for (int i = 0; i < 4; ++i) {
    int slot = i * 256 + t;
    int kk = slot >> 4;
    int c4 = slot & 15;
    float4 wv = *(const float4*)&W[(size_t)kk * 64 + c4 * 4];
    *(float4*)&Wl[kk][c4 * 4] = wv;
  }
  if (t < 64) bias[t] = bb[t];
  __syncthreads();

  int c0 = (t & 15) * 4;
  int r0 = (t >> 4) * 4;
  float acc[4][4];
#pragma unroll
  for (int i = 0; i < 4; ++i)
#pragma unroll
    for (int j = 0; j < 4; ++j) acc[i][j] = 0.f;
#pragma unroll 8
  for (int kk = 0; kk < 64; ++kk) {
    float4 xv = *(const float4*)&Xt[kk][r0];
    float4 wv = *(const float4*)&Wl[kk][c0];
    float xr[4] = {xv.x, xv.y, xv.z, xv.w};
    float wc[4] = {wv.x, wv.y, wv.z, wv.w};
#pragma unroll
    for (int i = 0; i < 4; ++i)
#pragma unroll
      for (int j = 0; j < 4; ++j) acc[i][j] = fmaf(xr[i], wc[j], acc[i][j]);
  }
#pragma unroll
  for (int i = 0; i < 4; ++i) {
    int row = rbase + r0 + i;
    if (row < N) {
      float4 ov;
      ov.x = acc[i][0] + bias[c0 + 0];
      ov.y = acc[i][1] + bias[c0 + 1];
      ov.z = acc[i][2] + bias[c0 + 2];
      ov.w = acc[i][3] + bias[c0 + 3];
      *(float4*)&o[(size_t)row * 64 + c0] = ov;
    }
  }
}

// ---------------- fused aggregation for BOTH directions: one WAVE per node (R14 unroll-4) ----------------
__global__ __launch_bounds__(256) void agg_all(
    const unsigned short* __restrict__ q_small, const unsigned short* __restrict__ kv_big,
    const int* __restrict__ rp_st, const int* __restrict__ es_st,
    float* __restrict__ xt_nxt, unsigned short* __restrict__ xtb_nxt,
    const unsigned short* __restrict__ q_big, const unsigned short* __restrict__ kv_small,
    const int* __restrict__ rp_ts, const int* __restrict__ es_ts,
    float* __restrict__ xs_nxt, unsigned short* __restrict__ xsb_nxt,
    int relu, int stBlocks) {
  const unsigned short* q; const unsigned short* kvi; const int* rowptr; const int* eisrc;
  float* xout; unsigned short* xoutb; int node;
  int wv = threadIdx.x >> 6, l = threadIdx.x & 63;
  if ((int)blockIdx.x < stBlocks) {
    node = blockIdx.x * 4 + wv;
    if (node >= NTGT) return;
    q = q_small; kvi = kv_big; rowptr = rp_st; eisrc = es_st; xout = xt_nxt; xoutb = xtb_nxt;
  } else {
    node = (blockIdx.x - stBlocks) * 4 + wv;
    if (node >= NSRC) return;
    q = q_big; kvi = kv_small; rowptr = rp_ts; eisrc = es_ts; xout = xs_nxt; xoutb = xsb_nxt;
  }
  int j = l & 15;
  float4 qf = bf4_to_f4(*(const bf4*)&q[(size_t)node * QK + l * 4]);
  qf.x *= 0.125f; qf.y *= 0.125f; qf.z *= 0.125f; qf.w *= 0.125f;
  int beg = rowptr[node], end = rowptr[node + 1];

  float lsum = 0.f;
  float4 acc = make_float4(0.f, 0.f, 0.f, 0.f);
  int p = beg;
  for (; p + 4 <= end; p += 4) {
    int s0 = eisrc[p], s1 = eisrc[p + 1], s2 = eisrc[p + 2], s3 = eisrc[p + 3];
    uint4 a0 = *(const uint4*)&kvi[(size_t)s0 * 512 + l * 8];
    uint4 a1 = *(const uint4*)&kvi[(size_t)s1 * 512 + l * 8];
    uint4 a2 = *(const uint4*)&kvi[(size_t)s2 * 512 + l * 8];
    uint4 a3 = *(const uint4*)&kvi[(size_t)s3 * 512 + l * 8];
    float t0 = qf.x * lo_f(a0.x) + qf.y * lo_f(a0.y) + qf.z * lo_f(a0.z) + qf.w * lo_f(a0.w);
    float t1 = qf.x * lo_f(a1.x) + qf.y * lo_f(a1.y) + qf.z * lo_f(a1.z) + qf.w * lo_f(a1.w);
    float t2 = qf.x * lo_f(a2.x) + qf.y * lo_f(a2.y) + qf.z * lo_f(a2.z) + qf.w * lo_f(a2.w);
    float t3 = qf.x * lo_f(a3.x) + qf.y * lo_f(a3.y) + qf.z * lo_f(a3.z) + qf.w * lo_f(a3.w);
#pragma unroll
    for (int o = 1; o < 16; o <<= 1) {
      t0 += __shfl_xor(t0, o, 16); t1 += __shfl_xor(t1, o, 16);
      t2 += __shfl_xor(t2, o, 16); t3 += __shfl_xor(t3, o, 16);
    }
    float w0 = __expf(t0), w1 = __expf(t1), w2 = __expf(t2), w3 = __expf(t3);
    lsum += (w0 + w1) + (w2 + w3);
    acc.x = fmaf(w0, hi_f(a0.x), fmaf(w1, hi_f(a1.x), fmaf(w2, hi_f(a2.x), fmaf(w3, hi_f(a3.x), acc.x))));
    acc.y = fmaf(w0, hi_f(a0.y), fmaf(w1, hi_f(a1.y), fmaf(w2, hi_f(a2.y), fmaf(w3, hi_f(a3.y), acc.y))));
    acc.z = fmaf(w0, hi_f(a0.z), fmaf(w1, hi_f(a1.z), fmaf(w2, hi_f(a2.z), fmaf(w3, hi_f(a3.z), acc.z))));
    acc.w = fmaf(w0, hi_f(a0.w), fmaf(w1, hi_f(a1.w), fmaf(w2, hi_f(a2.w), fmaf(w3, hi_f(a3.w), acc.w))));
  }
  for (; p < end; ++p) {
    int s0 = eisrc[p];
    uint4 a0 = *(const uint4*)&kvi[(size_t)s0 * 512 + l * 8];
    float s = qf.x * lo_f(a0.x) + qf.y * lo_f(a0.y) + qf.z * lo_f(a0.z) + qf.w * lo_f(a0.w);
#pragma unroll
    for (int o = 1; o < 16; o <<= 1) s += __shfl_xor(s, o, 16);
    float w = __expf(s);
    lsum += w;
    acc.x = fmaf(w, hi_f(a0.x), acc.x);
    acc.y = fmaf(w, hi_f(a0.y), acc.y);
    acc.z = fmaf(w, hi_f(a0.z), acc.z);
    acc.w = fmaf(w, hi_f(a0.w), acc.w);
  }

  float inv = (lsum > 0.f) ? 1.f / lsum : 0.f;
  float4 r;
  r.x = acc.x * inv; r.y = acc.y * inv; r.z = acc.z * inv; r.w = acc.w * inv;
  r.x += __shfl_xor(r.x, 16, 64); r.x += __shfl_xor(r.x, 32, 64);
  r.y += __shfl_xor(r.y, 16, 64); r.y += __shfl_xor(r.y, 32, 64);
  r.z += __shfl_xor(r.z, 16, 64); r.z += __shfl_xor(r.z, 32, 64);
  r.w += __shfl_xor(r.w, 16, 64); r.w += __shfl_xor(r.w, 32, 64);
  if (l < 16) {
    float4 sk = *(const float4*)&xout[(size_t)node * HD + j * 4];
    float4 o;
    o.x = sk.x + 0.25f * r.x;
    o.y = sk.y + 0.25f * r.y;
    o.z = sk.z + 0.25f * r.z;
    o.w = sk.w + 0.25f * r.w;
    if (relu) {
      o.x = fmaxf(o.x, 0.f); o.y = fmaxf(o.y, 0.f);
      o.z = fmaxf(o.z, 0.f); o.w = fmaxf(o.w, 0.f);
    }
    *(float4*)&xout[(size_t)node * HD + j * 4] = o;
    bf4 ob;
    ob.x = f2bf(o.x); ob.y = f2bf(o.y); ob.z = f2bf(o.z); ob.w = f2bf(o.w);
    *(bf4*)&xoutb[(size_t)node * HD + j * 4] = ob;
  }
}

// ---------------- classifier: 16 lanes per pair, float4 loads ----------------
__global__ __launch_bounds__(256) void classifier_kernel(const float* __restrict__ xs, const float* __restrict__ xt,
    const int* __restrict__ ls, const int* __restrict__ lt, float* __restrict__ out, int n) {
  int g = blockIdx.x * 256 + threadIdx.x;
  int pair = g >> 4, j = g & 15;
  if (pair >= n) return;
  int a = ls[pair], b = lt[pair];
  float4 xa = *(const float4*)&xs[(size_t)a * HD + j * 4];
  float4 xb = *(const float4*)&xt[(size_t)b * HD + j * 4];
  float s = xa.x * xb.x + xa.y * xb.y + xa.z * xb.z + xa.w * xb.w;
#pragma unroll
  for (int o = 1; o < 16; o <<= 1) s += __shfl_xor(s, o, 16);
  if (j == 0) out[pair] = s;
}

// ---------------- launch ----------------
extern "C" void kernel_launch(void* const* d_in, const int* in_sizes, int n_in,
                              void* d_out, int out_size, void* d_ws, size_t ws_size,
                              hipStream_t stream) {
  const float* src_emb = (const float*)d_in[0];
  const float* tgt_emb = (const float*)d_in[1];
  const float* Wq = (const float*)d_in[2];
  const float* bq = (const float*)d_in[3];
  const float* Wk = (const float*)d_in[4];
  const float* bk = (const float*)d_in[5];
  const float* Wv = (const float*)d_in[6];
  const float* bv = (const float*)d_in[7];
  const float* Wsk = (const float*)d_in[8];
  const float* bsk = (const float*)d_in[9];
  const int* nid_s = (const int*)d_in[10];
  const int* nid_t = (const int*)d_in[11];
  const int* e_st = (const int*)d_in[12];
  const int* e_ts = (const int*)d_in[13];
  const int* e_lbl = (const int*)d_in[14];
  float* out = (float*)d_out;

  char* ws = (char*)d_ws;
  size_t off = 0;
  auto alloc = [&](size_t bytes) -> void* {
    void* p = ws + off;
    off += (bytes + 255) & ~(size_t)255;
    return p;
  };
  unsigned int*   kv_big   = (unsigned int*)alloc((size_t)NSRC * 256 * 4);   // st k/v packed words
  unsigned short* q_big    = (unsigned short*)alloc((size_t)NSRC * QK * 2);  // ts q
  unsigned int*   kv_small = (unsigned int*)alloc((size_t)NTGT * 256 * 4);   // ts k/v packed words
  unsigned short* q_small  = (unsigned short*)alloc((size_t)NTGT * QK * 2);  // st q
  float* xsA = (float*)alloc((size_t)NSRC * HD * 4);
  float* xsB = (float*)alloc((size_t)NSRC * HD * 4);
  float* xtA = (float*)alloc((size_t)NTGT * HD * 4);
  float* xtB = (float*)alloc((size_t)NTGT * HD * 4);
  unsigned short* xsAb = (unsigned short*)alloc((size_t)NSRC * HD * 2);
  unsigned short* xsBb = (unsigned short*)alloc((size_t)NSRC * HD * 2);
  unsigned short* xtAb = (unsigned short*)alloc((size_t)NTGT * HD * 2);
  unsigned short* xtBb = (unsigned short*)alloc((size_t)NTGT * HD * 2);
  unsigned short* Wtq = (unsigned short*)alloc((size_t)4 * 16384 * 2);
  unsigned short* Wtk = (unsigned short*)alloc((size_t)4 * 16384 * 2);
  unsigned short* Wtv = (unsigned short*)alloc((size_t)4 * 16384 * 2);
  int* rp_st = (int*)alloc((size_t)(NTGT + 1) * 4);
  int* es_st = (int*)alloc((size_t)NEDGE * 4);
  int* rp_ts = (int*)alloc((size_t)(NSRC + 1) * 4);
  int* es_ts = (int*)alloc((size_t)NEDGE * 4);
  int* cursor = (int*)alloc((size_t)NTOT * 4);
  int* counts = (int*)alloc((size_t)NTOT * 4);
  int* incl_buf = (int*)alloc((size_t)NTOT * 4);
  int* blocksums = (int*)alloc(64 * 4);
  int* boff = (int*)alloc(64 * 4);
  (void)ws_size; (void)in_sizes; (void)n_in; (void)out_size;

  auto cdiv = [](int a, int b) { return (a + b - 1) / b; };
  const int GATHER_BLK = cdiv(NTOT * HD, 256);          // 15000
  const int SETUP_BLK = 48 + GATHER_BLK + cdiv(NTOT, 256);
  const int RT_S = cdiv(NSRC, 64);                      // 782
  const int RT_T = cdiv(NTGT, 64);                      // 157
  const int NBLK_PROJ = 2 * (NSRC / 16) + 2 * (NTGT / 16);  // kv+q = 7500
  const int ST_BLK = cdiv(NTGT, 4);                     // 2500
  const int NBLK_AGG = ST_BLK + cdiv(NSRC, 4);          // 15000

  // fused setup: weight transpose + feature gather + counts zero
  setup_kernel<<<SETUP_BLK, 256, 0, stream>>>(Wq, Wk, Wv, Wtq, Wtk, Wtv,
                                              src_emb, nid_s, tgt_emb, nid_t,
                                              xsA, xsAb, xtA, xtAb, counts, GATHER_BLK);

  // CSR build for both edge sets
  hist_all_kernel<<<cdiv(2 * NEDGE, 256), 256, 0, stream>>>(e_st, e_ts, counts);
  scan1_kernel<<<cdiv(NTOT, 1024), 256, 0, stream>>>(counts, incl_buf, blocksums, NTOT);
  scan2_kernel<<<1, 64, 0, stream>>>(blocksums, boff, cdiv(NTOT, 1024));
  scan3_kernel<<<cdiv(NTOT, 256), 256, 0, stream>>>(incl_buf, counts, boff, rp_st, rp_ts, cursor);
  scatter_all_kernel<<<cdiv(2 * NEDGE, 256), 256, 0, stream>>>(e_st, e_ts, cursor, es_st, es_ts);

  const float* xs_cur = xsA; float* xs_nxt = xsB;
  const float* xt_cur = xtA; float* xt_nxt = xtB;
  const unsigned short* xsb_cur = xsAb; unsigned short* xsb_nxt = xsBb;
  const unsigned short* xtb_cur = xtAb; unsigned short* xtb_nxt = xtBb;
  for (int l = 0; l < 2; ++l) {
    int relu = (l == 0) ? 1 : 0;
    int p_st = l * 2 + 0, p_ts = l * 2 + 1;
    proj_all<<<NBLK_PROJ, 256, 0, stream>>>(xsb_cur, xtb_cur, Wtq, Wtk, Wtv, bq, bk, bv,
                                            kv_big, q_big, kv_small, q_small, p_st, p_ts);
    skip_all<<<RT_S + RT_T, 256, 0, stream>>>(xs_cur, xt_cur, Wsk, bsk, xs_nxt, xt_nxt, p_st, p_ts, RT_S);
    agg_all<<<NBLK_AGG, 256, 0, stream>>>(q_small, (const unsigned short*)kv_big, rp_st, es_st, xt_nxt, xtb_nxt,
                                          q_big, (const unsigned short*)kv_small, rp_ts, es_ts, xs_nxt, xsb_nxt,
                                          relu, ST_BLK);
    { const float* t = xs_nxt; xs_nxt = (float*)xs_cur; xs_cur = t; }
    { const float* t = xt_nxt; xt_nxt = (float*)xt_cur; xt_cur = t; }
    { const unsigned short* t = xsb_nxt; xsb_nxt = (unsigned short*)xsb_cur; xsb_cur = t; }
    { const unsigned short* t = xtb_nxt; xtb_nxt = (unsigned short*)xtb_cur; xtb_cur = t; }
  }

  classifier_kernel<<<cdiv(NLBL * 16, 256), 256, 0, stream>>>(xs_cur, xt_cur, e_lbl, e_lbl + NLBL, out, NLBL);
}